// Round 1
// 182.173 us; speedup vs baseline: 1.0268x; 1.0268x over previous
//
#include <hip/hip_runtime.h>
#include <math.h>

typedef __bf16 bf16x8 __attribute__((ext_vector_type(8)));
typedef __bf16 bf16x4 __attribute__((ext_vector_type(4)));
typedef float  f32x4  __attribute__((ext_vector_type(4)));

// ---------------------------------------------------------------------------
// cvt: fp32 -> bf16 for the 4 weight matrices (512x512 each)
// ---------------------------------------------------------------------------
__global__ __launch_bounds__(256)
void cvt_w(const float* __restrict__ w0, const float* __restrict__ w1,
           const float* __restrict__ w2, const float* __restrict__ w3,
           __bf16* __restrict__ d0, __bf16* __restrict__ d1,
           __bf16* __restrict__ d2, __bf16* __restrict__ d3)
{
    const int y = blockIdx.y;
    const float* s = (y == 0) ? w0 : (y == 1) ? w1 : (y == 2) ? w2 : w3;
    __bf16*      d = (y == 0) ? d0 : (y == 1) ? d1 : (y == 2) ? d2 : d3;
    const int i = blockIdx.x * 256 + threadIdx.x;
    float4 a = *(const float4*)(s + (size_t)i * 8);
    float4 b = *(const float4*)(s + (size_t)i * 8 + 4);
    bf16x8 v;
    v[0] = (__bf16)a.x; v[1] = (__bf16)a.y; v[2] = (__bf16)a.z; v[3] = (__bf16)a.w;
    v[4] = (__bf16)b.x; v[5] = (__bf16)b.y; v[6] = (__bf16)b.z; v[7] = (__bf16)b.w;
    *(bf16x8*)(d + (size_t)i * 8) = v;
}

// ---------------------------------------------------------------------------
// Fused QKV projection. X fp32 (cvt on load), W bf16. Tile 64(M)x128(N).
// ---------------------------------------------------------------------------
__global__ __launch_bounds__(256)
void qkv_proj(const float* __restrict__ X,
              const __bf16* __restrict__ Wqb, const __bf16* __restrict__ Wkb,
              const __bf16* __restrict__ Wvb,
              const float* __restrict__ bq, const float* __restrict__ bk,
              const float* __restrict__ bv,
              __bf16* __restrict__ qTb, __bf16* __restrict__ kTb,
              __bf16* __restrict__ vTb)
{
    const int z = blockIdx.z;
    const __bf16* Wb   = (z == 0) ? Wqb : (z == 1) ? Wkb : Wvb;
    const float*  bias = (z == 0) ? bq  : (z == 1) ? bk  : bv;

    const int tid  = threadIdx.x;
    const int w    = tid >> 6;
    const int lane = tid & 63;
    const int lq   = lane & 15;
    const int quad = lane >> 4;
    const int n0    = blockIdx.x * 64 + (w >> 1) * 32;
    const int obase = blockIdx.y * 128 + (w & 1) * 64;

    f32x4 acc[2][4] = {};
    for (int k0 = 0; k0 < 512; k0 += 32) {
        bf16x8 af[2], bfr[4];
#pragma unroll
        for (int m = 0; m < 2; m++) {
            const float* xp = X + (size_t)(n0 + m * 16 + lq) * 512 + k0 + quad * 8;
            float4 x0 = *(const float4*)xp;
            float4 x1 = *(const float4*)(xp + 4);
            bf16x8 v;
            v[0] = (__bf16)x0.x; v[1] = (__bf16)x0.y; v[2] = (__bf16)x0.z; v[3] = (__bf16)x0.w;
            v[4] = (__bf16)x1.x; v[5] = (__bf16)x1.y; v[6] = (__bf16)x1.z; v[7] = (__bf16)x1.w;
            af[m] = v;
        }
#pragma unroll
        for (int nn = 0; nn < 4; nn++)
            bfr[nn] = *(const bf16x8*)(Wb + (size_t)(obase + nn * 16 + lq) * 512 + k0 + quad * 8);
#pragma unroll
        for (int m = 0; m < 2; m++)
#pragma unroll
            for (int nn = 0; nn < 4; nn++)
                acc[m][nn] = __builtin_amdgcn_mfma_f32_16x16x32_bf16(af[m], bfr[nn], acc[m][nn], 0, 0, 0);
    }

    const float scaling = 0.17677669529663687f;
#pragma unroll
    for (int m = 0; m < 2; m++)
#pragma unroll
        for (int nn = 0; nn < 4; nn++)
#pragma unroll
            for (int r = 0; r < 4; r++) {
                const int n = n0 + m * 16 + quad * 4 + r;
                const int o = obase + nn * 16 + lq;
                float val = acc[m][nn][r] + bias[o];
                const int t = n >> 2, b = n & 3;
                const int h = o >> 5, d = o & 31;
                const int bh = b * 16 + h;
                if (z == 0)
                    qTb[(((size_t)bh * 1024 + t) << 5) + d] = (__bf16)(val * scaling);
                else if (z == 1)
                    kTb[(((size_t)bh * 1024 + t) << 5) + d] = (__bf16)val;
                else
                    vTb[(((size_t)bh * 32 + d) << 10) + t] = (__bf16)val;
            }
}

// ---------------------------------------------------------------------------
// Out projection: A bf16 [4096][512], W bf16, out fp32 + bias. Tile 64x128.
// ---------------------------------------------------------------------------
__global__ __launch_bounds__(256)
void out_proj(const __bf16* __restrict__ A, const __bf16* __restrict__ Wb,
              const float* __restrict__ bias, float* __restrict__ out)
{
    const int tid  = threadIdx.x;
    const int w    = tid >> 6;
    const int lane = tid & 63;
    const int lq   = lane & 15;
    const int quad = lane >> 4;
    const int n0    = blockIdx.x * 64 + (w >> 1) * 32;
    const int obase = blockIdx.y * 128 + (w & 1) * 64;

    f32x4 acc[2][4] = {};
    for (int k0 = 0; k0 < 512; k0 += 32) {
        bf16x8 af[2], bfr[4];
#pragma unroll
        for (int m = 0; m < 2; m++)
            af[m] = *(const bf16x8*)(A + (size_t)(n0 + m * 16 + lq) * 512 + k0 + quad * 8);
#pragma unroll
        for (int nn = 0; nn < 4; nn++)
            bfr[nn] = *(const bf16x8*)(Wb + (size_t)(obase + nn * 16 + lq) * 512 + k0 + quad * 8);
#pragma unroll
        for (int m = 0; m < 2; m++)
#pragma unroll
            for (int nn = 0; nn < 4; nn++)
                acc[m][nn] = __builtin_amdgcn_mfma_f32_16x16x32_bf16(af[m], bfr[nn], acc[m][nn], 0, 0, 0);
    }
#pragma unroll
    for (int m = 0; m < 2; m++)
#pragma unroll
        for (int nn = 0; nn < 4; nn++)
#pragma unroll
            for (int r = 0; r < 4; r++) {
                const int n = n0 + m * 16 + quad * 4 + r;
                const int o = obase + nn * 16 + lq;
                out[(size_t)n * 512 + o] = acc[m][nn][r] + bias[o];
            }
}

// ---------------------------------------------------------------------------
// MFMA attention, 16 heads per block. Block = (t-tile 16, b). 8 waves; wave w
// owns s in [w*128,+128). Bias is loaded DIRECTLY into registers as the MFMA
// C-operand (f32x4 per lane per j-tile) and prefetched one head ahead; the
// per-head barrier is a raw s_barrier with lgkmcnt-only drain so the bias
// prefetch stays in flight across it. Op/red are double-buffered -> one
// barrier per head. avg accumulated over all 16 heads -> single fp32 store
// (p1 / avg_add eliminated).
// ---------------------------------------------------------------------------
__global__ __launch_bounds__(512, 2)
void attn_mfma(const __bf16* __restrict__ qTb, const __bf16* __restrict__ kTb,
               const __bf16* __restrict__ vTb, const float* __restrict__ bias,
               const int* __restrict__ mask, __bf16* __restrict__ attnb,
               float* __restrict__ avgf)
{
    // [0,8448): Op[2][8][528]  [8448,8704): red[2][8][16]
    // [8704,17408): P bf16 [8][16*136]
    __shared__ float smem[17408];
    float* const Op0  = smem;
    float* const red0 = &smem[8448];
    __bf16* const Pbase = (__bf16*)&smem[8704];

    const int tid  = threadIdx.x;
    const int w    = tid >> 6;
    const int lane = tid & 63;
    const int lq   = lane & 15;
    const int quad = lane >> 4;

    // bijective XCD swizzle: 256 blocks -> 32-block contiguous chunk per XCD
    const int bid = blockIdx.y * 64 + blockIdx.x;
    const int nb  = (bid & 7) * 32 + (bid >> 3);
    const int t0  = (nb & 63) * 16;
    const int b   = nb >> 6;
    const int sbase = w * 128;

    __bf16* const Pw = Pbase + w * 2176;   // 16*136 bf16 per wave

    // pack 32 mask bits (s = sbase + j*16 + quad*4 + r)
    unsigned mbits = 0;
    {
        const int* mp = mask + b * 1024 + sbase + quad * 4;
#pragma unroll
        for (int j = 0; j < 8; j++) {
            int4 m4 = *(const int4*)(mp + j * 16);
            mbits |= (unsigned)(m4.x != 0) << (j * 4 + 0);
            mbits |= (unsigned)(m4.y != 0) << (j * 4 + 1);
            mbits |= (unsigned)(m4.z != 0) << (j * 4 + 2);
            mbits |= (unsigned)(m4.w != 0) << (j * 4 + 3);
        }
    }

    // bias C-operand base for this lane: bias[bh][t0+lq][sbase + quad*4 + j*16]
    const float* const bb = bias + (((size_t)(b * 16)) << 20) +
                            (((size_t)(t0 + lq)) << 10) + sbase + quad * 4;
    const __bf16* const qp0 = qTb + (((size_t)(b * 16) * 1024 + t0) << 5) +
                              lq * 32 + quad * 8;

    // prologue: head 0 bias + Q into registers
    f32x4 cj[8];
#pragma unroll
    for (int j = 0; j < 8; j++) cj[j] = *(const f32x4*)(bb + j * 16);
    bf16x8 qa = *(const bf16x8*)qp0;

    float avg_reg[32] = {};

    for (int hh = 0; hh < 16; hh++) {
        const int bh = b * 16 + hh;
        float* const Op  = Op0  + (hh & 1) * 4224;
        float* const red = red0 + (hh & 1) * 128;
        const __bf16* kp = kTb + ((size_t)bh << 15);
        const __bf16* vp = vTb + ((size_t)bh << 15);

        // QK: C-operand comes straight from the bias registers
        f32x4 acc[8];
#pragma unroll
        for (int j = 0; j < 8; j++) {
            bf16x8 kb = *(const bf16x8*)(kp + (size_t)(sbase + j * 16 + lq) * 32 + quad * 8);
            acc[j] = __builtin_amdgcn_mfma_f32_16x16x32_bf16(kb, qa, cj[j], 0, 0, 0);
        }

        // prefetch next head's bias + Q now; in flight through exp/PV/reduce
        // and across the raw barrier (no vmcnt drain there).
        if (hh < 15) {
            const float* bn = bb + ((size_t)(hh + 1) << 20);
#pragma unroll
            for (int j = 0; j < 8; j++) cj[j] = *(const f32x4*)(bn + j * 16);
            qa = *(const bf16x8*)(qp0 + ((size_t)(hh + 1) << 15));
        }

        // exp (no max pass; scores bounded) + mask + row partial sum
        float sm = 0.f;
#pragma unroll
        for (int j = 0; j < 8; j++)
#pragma unroll
            for (int r = 0; r < 4; r++) {
                float p = __expf(acc[j][r]);
                p = ((mbits >> (j * 4 + r)) & 1u) ? 0.f : p;
                acc[j][r] = p;
                sm += p;
            }
        sm += __shfl_xor(sm, 16);
        sm += __shfl_xor(sm, 32);

        // unnormalized bf16 P into per-wave LDS region (same-wave use only)
#pragma unroll
        for (int j = 0; j < 8; j++) {
            bf16x4 pv;
            pv[0] = (__bf16)acc[j][0]; pv[1] = (__bf16)acc[j][1];
            pv[2] = (__bf16)acc[j][2]; pv[3] = (__bf16)acc[j][3];
            *(bf16x4*)&Pw[lq * 136 + j * 16 + quad * 4] = pv;
        }
        if (lane < 16) red[w * 16 + lane] = sm;

        // PV on the wave's own P region (same-wave LDS ordering via lgkmcnt)
        f32x4 o0 = {0.f, 0.f, 0.f, 0.f}, o1 = {0.f, 0.f, 0.f, 0.f};
#pragma unroll
        for (int ks = 0; ks < 4; ks++) {
            bf16x8 pa = *(const bf16x8*)&Pw[lq * 136 + ks * 32 + quad * 8];
            bf16x8 v0 = *(const bf16x8*)(vp + (size_t)lq * 1024 + sbase + ks * 32 + quad * 8);
            bf16x8 v1 = *(const bf16x8*)(vp + (size_t)(16 + lq) * 1024 + sbase + ks * 32 + quad * 8);
            o0 = __builtin_amdgcn_mfma_f32_16x16x32_bf16(pa, v0, o0, 0, 0, 0);
            o1 = __builtin_amdgcn_mfma_f32_16x16x32_bf16(pa, v1, o1, 0, 0, 0);
        }
#pragma unroll
        for (int r = 0; r < 4; r++) {
            Op[w * 528 + (quad * 4 + r) * 33 + lq]      = o0[r];
            Op[w * 528 + (quad * 4 + r) * 33 + 16 + lq] = o1[r];
        }

        // raw barrier: drain LDS only; bias prefetch (VMEM) stays in flight.
        // Op/red double-buffering makes one barrier per head sufficient: this
        // head's reads are lgkm-drained before the NEXT head's barrier, which
        // orders them against the head-after-next's writes to this buffer.
        __builtin_amdgcn_sched_barrier(0);
        asm volatile("s_waitcnt lgkmcnt(0)" ::: "memory");
        __builtin_amdgcn_s_barrier();
        __builtin_amdgcn_sched_barrier(0);

        // cross-wave reduce: normalized O write
        {
            const int t = tid >> 5, d = tid & 31;
            float s = 0.f, o = 0.f;
#pragma unroll
            for (int w2 = 0; w2 < 8; w2++) s += red[w2 * 16 + t];
#pragma unroll
            for (int w2 = 0; w2 < 8; w2++) o += Op[w2 * 528 + t * 33 + d];
            attnb[((size_t)(t0 + t) * 4 + b) * 512 + hh * 32 + d] = (__bf16)(o / s);
        }

        // inv for this lane's rows (t = lq) + avg fold; acc dies here
        float s_all = 0.f;
#pragma unroll
        for (int w2 = 0; w2 < 8; w2++) s_all += red[w2 * 16 + lq];
        const float inv = 1.0f / s_all;
#pragma unroll
        for (int j = 0; j < 8; j++)
#pragma unroll
            for (int r = 0; r < 4; r++)
                avg_reg[j * 4 + r] += acc[j][r] * inv;
    }

    // head-mean store: single fp32 write (all 16 heads accumulated here)
    float* ap = avgf + ((size_t)(b * 1024 + t0 + lq) << 10) + sbase + quad * 4;
#pragma unroll
    for (int j = 0; j < 8; j++) {
        f32x4 v = { avg_reg[j * 4 + 0] * 0.0625f, avg_reg[j * 4 + 1] * 0.0625f,
                    avg_reg[j * 4 + 2] * 0.0625f, avg_reg[j * 4 + 3] * 0.0625f };
        *(f32x4*)(ap + j * 16) = v;
    }
}

// ---------------------------------------------------------------------------
extern "C" void kernel_launch(void* const* d_in, const int* in_sizes, int n_in,
                              void* d_out, int out_size, void* d_ws, size_t ws_size,
                              hipStream_t stream)
{
    const float* query     = (const float*)d_in[0];
    const float* attn_bias = (const float*)d_in[1];
    const int*   mask      = (const int*)d_in[2];
    const float* q_w       = (const float*)d_in[3];
    const float* q_b       = (const float*)d_in[4];
    const float* k_w       = (const float*)d_in[5];
    const float* k_b       = (const float*)d_in[6];
    const float* v_w       = (const float*)d_in[7];
    const float* v_b       = (const float*)d_in[8];
    const float* out_w     = (const float*)d_in[9];
    const float* out_b     = (const float*)d_in[10];

    float* out     = (float*)d_out;                 // [1024,4,512]
    float* avg_out = out + (size_t)2097152;         // [4,1024,1024]

    char* wsb = (char*)d_ws;
    __bf16* Wqb   = (__bf16*)(wsb);                         // 512 KB
    __bf16* Wkb   = (__bf16*)(wsb + ((size_t)512 << 10));
    __bf16* Wvb   = (__bf16*)(wsb + ((size_t)1 << 20));
    __bf16* Wob   = (__bf16*)(wsb + ((size_t)1 << 20) + ((size_t)512 << 10));
    __bf16* qTb   = (__bf16*)(wsb + ((size_t)2  << 20));    // 4 MB [64][1024][32]
    __bf16* kTb   = (__bf16*)(wsb + ((size_t)6  << 20));    // 4 MB [64][1024][32]
    __bf16* vTb   = (__bf16*)(wsb + ((size_t)10 << 20));    // 4 MB [64][32][1024]
    __bf16* attnb = (__bf16*)(wsb + ((size_t)14 << 20));    // 4 MB [4096][512]

    cvt_w<<<dim3(128, 4), dim3(256), 0, stream>>>(
        q_w, k_w, v_w, out_w, Wqb, Wkb, Wvb, Wob);

    qkv_proj<<<dim3(64, 4, 3), dim3(256), 0, stream>>>(
        query, Wqb, Wkb, Wvb, q_b, k_b, v_b, qTb, kTb, vTb);

    attn_mfma<<<dim3(64, 4), dim3(512), 0, stream>>>(
        qTb, kTb, vTb, attn_bias, mask, attnb, avg_out);

    out_proj<<<dim3(64, 4), dim3(256), 0, stream>>>(attnb, Wob, out_b, out);
}

// Round 2
// 157.927 us; speedup vs baseline: 1.1845x; 1.1535x over previous
//
#include <hip/hip_runtime.h>
#include <math.h>

typedef __bf16 bf16x8 __attribute__((ext_vector_type(8)));
typedef __bf16 bf16x4 __attribute__((ext_vector_type(4)));
typedef float  f32x4  __attribute__((ext_vector_type(4)));

// ---------------------------------------------------------------------------
// cvt: fp32 -> bf16 for the 4 weight matrices (512x512 each)
// ---------------------------------------------------------------------------
__global__ __launch_bounds__(256)
void cvt_w(const float* __restrict__ w0, const float* __restrict__ w1,
           const float* __restrict__ w2, const float* __restrict__ w3,
           __bf16* __restrict__ d0, __bf16* __restrict__ d1,
           __bf16* __restrict__ d2, __bf16* __restrict__ d3)
{
    const int y = blockIdx.y;
    const float* s = (y == 0) ? w0 : (y == 1) ? w1 : (y == 2) ? w2 : w3;
    __bf16*      d = (y == 0) ? d0 : (y == 1) ? d1 : (y == 2) ? d2 : d3;
    const int i = blockIdx.x * 256 + threadIdx.x;
    float4 a = *(const float4*)(s + (size_t)i * 8);
    float4 b = *(const float4*)(s + (size_t)i * 8 + 4);
    bf16x8 v;
    v[0] = (__bf16)a.x; v[1] = (__bf16)a.y; v[2] = (__bf16)a.z; v[3] = (__bf16)a.w;
    v[4] = (__bf16)b.x; v[5] = (__bf16)b.y; v[6] = (__bf16)b.z; v[7] = (__bf16)b.w;
    *(bf16x8*)(d + (size_t)i * 8) = v;
}

// ---------------------------------------------------------------------------
// Fused QKV projection. X fp32 (cvt on load), W bf16. Tile 64(M)x128(N).
// ---------------------------------------------------------------------------
__global__ __launch_bounds__(256)
void qkv_proj(const float* __restrict__ X,
              const __bf16* __restrict__ Wqb, const __bf16* __restrict__ Wkb,
              const __bf16* __restrict__ Wvb,
              const float* __restrict__ bq, const float* __restrict__ bk,
              const float* __restrict__ bv,
              __bf16* __restrict__ qTb, __bf16* __restrict__ kTb,
              __bf16* __restrict__ vTb)
{
    const int z = blockIdx.z;
    const __bf16* Wb   = (z == 0) ? Wqb : (z == 1) ? Wkb : Wvb;
    const float*  bias = (z == 0) ? bq  : (z == 1) ? bk  : bv;

    const int tid  = threadIdx.x;
    const int w    = tid >> 6;
    const int lane = tid & 63;
    const int lq   = lane & 15;
    const int quad = lane >> 4;
    const int n0    = blockIdx.x * 64 + (w >> 1) * 32;
    const int obase = blockIdx.y * 128 + (w & 1) * 64;

    f32x4 acc[2][4] = {};
    for (int k0 = 0; k0 < 512; k0 += 32) {
        bf16x8 af[2], bfr[4];
#pragma unroll
        for (int m = 0; m < 2; m++) {
            const float* xp = X + (size_t)(n0 + m * 16 + lq) * 512 + k0 + quad * 8;
            float4 x0 = *(const float4*)xp;
            float4 x1 = *(const float4*)(xp + 4);
            bf16x8 v;
            v[0] = (__bf16)x0.x; v[1] = (__bf16)x0.y; v[2] = (__bf16)x0.z; v[3] = (__bf16)x0.w;
            v[4] = (__bf16)x1.x; v[5] = (__bf16)x1.y; v[6] = (__bf16)x1.z; v[7] = (__bf16)x1.w;
            af[m] = v;
        }
#pragma unroll
        for (int nn = 0; nn < 4; nn++)
            bfr[nn] = *(const bf16x8*)(Wb + (size_t)(obase + nn * 16 + lq) * 512 + k0 + quad * 8);
#pragma unroll
        for (int m = 0; m < 2; m++)
#pragma unroll
            for (int nn = 0; nn < 4; nn++)
                acc[m][nn] = __builtin_amdgcn_mfma_f32_16x16x32_bf16(af[m], bfr[nn], acc[m][nn], 0, 0, 0);
    }

    const float scaling = 0.17677669529663687f;
#pragma unroll
    for (int m = 0; m < 2; m++)
#pragma unroll
        for (int nn = 0; nn < 4; nn++)
#pragma unroll
            for (int r = 0; r < 4; r++) {
                const int n = n0 + m * 16 + quad * 4 + r;
                const int o = obase + nn * 16 + lq;
                float val = acc[m][nn][r] + bias[o];
                const int t = n >> 2, b = n & 3;
                const int h = o >> 5, d = o & 31;
                const int bh = b * 16 + h;
                if (z == 0)
                    qTb[(((size_t)bh * 1024 + t) << 5) + d] = (__bf16)(val * scaling);
                else if (z == 1)
                    kTb[(((size_t)bh * 1024 + t) << 5) + d] = (__bf16)val;
                else
                    vTb[(((size_t)bh * 32 + d) << 10) + t] = (__bf16)val;
            }
}

// ---------------------------------------------------------------------------
// Out projection: A bf16 [4096][512], W bf16, out fp32 + bias. Tile 64x128.
// ---------------------------------------------------------------------------
__global__ __launch_bounds__(256)
void out_proj(const __bf16* __restrict__ A, const __bf16* __restrict__ Wb,
              const float* __restrict__ bias, float* __restrict__ out)
{
    const int tid  = threadIdx.x;
    const int w    = tid >> 6;
    const int lane = tid & 63;
    const int lq   = lane & 15;
    const int quad = lane >> 4;
    const int n0    = blockIdx.x * 64 + (w >> 1) * 32;
    const int obase = blockIdx.y * 128 + (w & 1) * 64;

    f32x4 acc[2][4] = {};
    for (int k0 = 0; k0 < 512; k0 += 32) {
        bf16x8 af[2], bfr[4];
#pragma unroll
        for (int m = 0; m < 2; m++)
            af[m] = *(const bf16x8*)(A + (size_t)(n0 + m * 16 + lq) * 512 + k0 + quad * 8);
#pragma unroll
        for (int nn = 0; nn < 4; nn++)
            bfr[nn] = *(const bf16x8*)(Wb + (size_t)(obase + nn * 16 + lq) * 512 + k0 + quad * 8);
#pragma unroll
        for (int m = 0; m < 2; m++)
#pragma unroll
            for (int nn = 0; nn < 4; nn++)
                acc[m][nn] = __builtin_amdgcn_mfma_f32_16x16x32_bf16(af[m], bfr[nn], acc[m][nn], 0, 0, 0);
    }
#pragma unroll
    for (int m = 0; m < 2; m++)
#pragma unroll
        for (int nn = 0; nn < 4; nn++)
#pragma unroll
            for (int r = 0; r < 4; r++) {
                const int n = n0 + m * 16 + quad * 4 + r;
                const int o = obase + nn * 16 + lq;
                out[(size_t)n * 512 + o] = acc[m][nn][r] + bias[o];
            }
}

// ---------------------------------------------------------------------------
// MFMA attention, 16 heads per block. Block = (t-tile 16, b). 8 waves; wave w
// owns s in [w*128,+128).
//
// VMEM ORDERING IS THE POINT: vmcnt is an in-order counter, so any wait on a
// young fast load drains all older loads first. Per head we therefore issue
//   (1) K loads (consumed immediately by QK),
//   (2) ALL V loads for this head (hoisted out of the PV loop, into regs),
//   (3) -- sched_barrier(0) pin --
//   (4) qa(h+1) then bias cj(h+1) prefetch   <- youngest VMEM of the head.
// Nothing after (4) waits on VMEM until QK(h+1) consumes qa/cj, so the bias
// prefetch stays in flight for a full head period (~6.5k cy) instead of
// ~300 cy. PV reads P from LDS (lgkmcnt) and V from registers.
// Raw s_barrier with lgkmcnt-only drain per head; Op/red double-buffered.
// ---------------------------------------------------------------------------
__global__ __launch_bounds__(512, 2)
void attn_mfma(const __bf16* __restrict__ qTb, const __bf16* __restrict__ kTb,
               const __bf16* __restrict__ vTb, const float* __restrict__ bias,
               const int* __restrict__ mask, __bf16* __restrict__ attnb,
               float* __restrict__ avgf)
{
    // [0,8448): Op[2][8][528]  [8448,8704): red[2][8][16]
    // [8704,17408): P bf16 [8][16*136]
    __shared__ float smem[17408];
    float* const Op0  = smem;
    float* const red0 = &smem[8448];
    __bf16* const Pbase = (__bf16*)&smem[8704];

    const int tid  = threadIdx.x;
    const int w    = tid >> 6;
    const int lane = tid & 63;
    const int lq   = lane & 15;
    const int quad = lane >> 4;

    // bijective XCD swizzle: 256 blocks -> 32-block contiguous chunk per XCD
    const int bid = blockIdx.y * 64 + blockIdx.x;
    const int nb  = (bid & 7) * 32 + (bid >> 3);
    const int t0  = (nb & 63) * 16;
    const int b   = nb >> 6;
    const int sbase = w * 128;

    __bf16* const Pw = Pbase + w * 2176;   // 16*136 bf16 per wave

    // pack 32 mask bits (s = sbase + j*16 + quad*4 + r)
    unsigned mbits = 0;
    {
        const int* mp = mask + b * 1024 + sbase + quad * 4;
#pragma unroll
        for (int j = 0; j < 8; j++) {
            int4 m4 = *(const int4*)(mp + j * 16);
            mbits |= (unsigned)(m4.x != 0) << (j * 4 + 0);
            mbits |= (unsigned)(m4.y != 0) << (j * 4 + 1);
            mbits |= (unsigned)(m4.z != 0) << (j * 4 + 2);
            mbits |= (unsigned)(m4.w != 0) << (j * 4 + 3);
        }
    }

    // bias C-operand base for this lane: bias[bh][t0+lq][sbase + quad*4 + j*16]
    const float* const bb = bias + (((size_t)(b * 16)) << 20) +
                            (((size_t)(t0 + lq)) << 10) + sbase + quad * 4;
    const __bf16* const qp0 = qTb + (((size_t)(b * 16) * 1024 + t0) << 5) +
                              lq * 32 + quad * 8;

    // prologue: head 0 Q + bias into registers (q first, so QK's first wait
    // leaves cj[1..7] outstanding)
    bf16x8 qa = *(const bf16x8*)qp0;
    f32x4 cj[8];
#pragma unroll
    for (int j = 0; j < 8; j++) cj[j] = *(const f32x4*)(bb + j * 16);

    float avg_reg[32] = {};

    for (int hh = 0; hh < 16; hh++) {
        const int bh = b * 16 + hh;
        float* const Op  = Op0  + (hh & 1) * 4224;
        float* const red = red0 + (hh & 1) * 128;
        const __bf16* kp = kTb + ((size_t)bh << 15);
        const __bf16* vp = vTb + ((size_t)bh << 15);

        // QK: C-operand comes straight from the bias registers. The vmcnt
        // wait here is the ONLY consumption point of last head's prefetch.
        f32x4 acc[8];
#pragma unroll
        for (int j = 0; j < 8; j++) {
            bf16x8 kb = *(const bf16x8*)(kp + (size_t)(sbase + j * 16 + lq) * 32 + quad * 8);
            acc[j] = __builtin_amdgcn_mfma_f32_16x16x32_bf16(kb, qa, cj[j], 0, 0, 0);
        }

        // V loads for THIS head, hoisted ahead of the bias prefetch so every
        // later intra-head wait targets only loads OLDER than the prefetch.
        bf16x8 v0r[4], v1r[4];
#pragma unroll
        for (int ks = 0; ks < 4; ks++) {
            v0r[ks] = *(const bf16x8*)(vp + (size_t)lq * 1024 + sbase + ks * 32 + quad * 8);
            v1r[ks] = *(const bf16x8*)(vp + (size_t)(16 + lq) * 1024 + sbase + ks * 32 + quad * 8);
        }

        // pin: bias prefetch must not be scheduled above the V loads
        __builtin_amdgcn_sched_barrier(0);

        // prefetch next head's Q + bias now: youngest VMEM of this head, in
        // flight through exp/PV/reduce and across the raw barrier.
        if (hh < 15) {
            qa = *(const bf16x8*)(qp0 + ((size_t)(hh + 1) << 15));
            const float* bn = bb + ((size_t)(hh + 1) << 20);
#pragma unroll
            for (int j = 0; j < 8; j++) cj[j] = *(const f32x4*)(bn + j * 16);
        }

        // exp (no max pass; scores bounded) + mask + row partial sum
        float sm = 0.f;
#pragma unroll
        for (int j = 0; j < 8; j++)
#pragma unroll
            for (int r = 0; r < 4; r++) {
                float p = __expf(acc[j][r]);
                p = ((mbits >> (j * 4 + r)) & 1u) ? 0.f : p;
                acc[j][r] = p;
                sm += p;
            }
        sm += __shfl_xor(sm, 16);
        sm += __shfl_xor(sm, 32);

        // unnormalized bf16 P into per-wave LDS region (same-wave use only)
#pragma unroll
        for (int j = 0; j < 8; j++) {
            bf16x4 pv;
            pv[0] = (__bf16)acc[j][0]; pv[1] = (__bf16)acc[j][1];
            pv[2] = (__bf16)acc[j][2]; pv[3] = (__bf16)acc[j][3];
            *(bf16x4*)&Pw[lq * 136 + j * 16 + quad * 4] = pv;
        }
        if (lane < 16) red[w * 16 + lane] = sm;

        // PV: P from LDS (lgkmcnt only), V from registers (no VMEM waits)
        f32x4 o0 = {0.f, 0.f, 0.f, 0.f}, o1 = {0.f, 0.f, 0.f, 0.f};
#pragma unroll
        for (int ks = 0; ks < 4; ks++) {
            bf16x8 pa = *(const bf16x8*)&Pw[lq * 136 + ks * 32 + quad * 8];
            o0 = __builtin_amdgcn_mfma_f32_16x16x32_bf16(pa, v0r[ks], o0, 0, 0, 0);
            o1 = __builtin_amdgcn_mfma_f32_16x16x32_bf16(pa, v1r[ks], o1, 0, 0, 0);
        }
#pragma unroll
        for (int r = 0; r < 4; r++) {
            Op[w * 528 + (quad * 4 + r) * 33 + lq]      = o0[r];
            Op[w * 528 + (quad * 4 + r) * 33 + 16 + lq] = o1[r];
        }

        // raw barrier: drain LDS only; bias prefetch (VMEM) stays in flight.
        __builtin_amdgcn_sched_barrier(0);
        asm volatile("s_waitcnt lgkmcnt(0)" ::: "memory");
        __builtin_amdgcn_s_barrier();
        __builtin_amdgcn_sched_barrier(0);

        // cross-wave reduce: normalized O write
        {
            const int t = tid >> 5, d = tid & 31;
            float s = 0.f, o = 0.f;
#pragma unroll
            for (int w2 = 0; w2 < 8; w2++) s += red[w2 * 16 + t];
#pragma unroll
            for (int w2 = 0; w2 < 8; w2++) o += Op[w2 * 528 + t * 33 + d];
            attnb[((size_t)(t0 + t) * 4 + b) * 512 + hh * 32 + d] = (__bf16)(o / s);
        }

        // inv for this lane's rows (t = lq) + avg fold; acc dies here
        float s_all = 0.f;
#pragma unroll
        for (int w2 = 0; w2 < 8; w2++) s_all += red[w2 * 16 + lq];
        const float inv = 1.0f / s_all;
#pragma unroll
        for (int j = 0; j < 8; j++)
#pragma unroll
            for (int r = 0; r < 4; r++)
                avg_reg[j * 4 + r] += acc[j][r] * inv;
    }

    // head-mean store: single fp32 write (all 16 heads accumulated here)
    float* ap = avgf + ((size_t)(b * 1024 + t0 + lq) << 10) + sbase + quad * 4;
#pragma unroll
    for (int j = 0; j < 8; j++) {
        f32x4 v = { avg_reg[j * 4 + 0] * 0.0625f, avg_reg[j * 4 + 1] * 0.0625f,
                    avg_reg[j * 4 + 2] * 0.0625f, avg_reg[j * 4 + 3] * 0.0625f };
        *(f32x4*)(ap + j * 16) = v;
    }
}

// ---------------------------------------------------------------------------
extern "C" void kernel_launch(void* const* d_in, const int* in_sizes, int n_in,
                              void* d_out, int out_size, void* d_ws, size_t ws_size,
                              hipStream_t stream)
{
    const float* query     = (const float*)d_in[0];
    const float* attn_bias = (const float*)d_in[1];
    const int*   mask      = (const int*)d_in[2];
    const float* q_w       = (const float*)d_in[3];
    const float* q_b       = (const float*)d_in[4];
    const float* k_w       = (const float*)d_in[5];
    const float* k_b       = (const float*)d_in[6];
    const float* v_w       = (const float*)d_in[7];
    const float* v_b       = (const float*)d_in[8];
    const float* out_w     = (const float*)d_in[9];
    const float* out_b     = (const float*)d_in[10];

    float* out     = (float*)d_out;                 // [1024,4,512]
    float* avg_out = out + (size_t)2097152;         // [4,1024,1024]

    char* wsb = (char*)d_ws;
    __bf16* Wqb   = (__bf16*)(wsb);                         // 512 KB
    __bf16* Wkb   = (__bf16*)(wsb + ((size_t)512 << 10));
    __bf16* Wvb   = (__bf16*)(wsb + ((size_t)1 << 20));
    __bf16* Wob   = (__bf16*)(wsb + ((size_t)1 << 20) + ((size_t)512 << 10));
    __bf16* qTb   = (__bf16*)(wsb + ((size_t)2  << 20));    // 4 MB [64][1024][32]
    __bf16* kTb   = (__bf16*)(wsb + ((size_t)6  << 20));    // 4 MB [64][1024][32]
    __bf16* vTb   = (__bf16*)(wsb + ((size_t)10 << 20));    // 4 MB [64][32][1024]
    __bf16* attnb = (__bf16*)(wsb + ((size_t)14 << 20));    // 4 MB [4096][512]

    cvt_w<<<dim3(128, 4), dim3(256), 0, stream>>>(
        q_w, k_w, v_w, out_w, Wqb, Wkb, Wvb, Wob);

    qkv_proj<<<dim3(64, 4, 3), dim3(256), 0, stream>>>(
        query, Wqb, Wkb, Wvb, q_b, k_b, v_b, qTb, kTb, vTb);

    attn_mfma<<<dim3(64, 4), dim3(512), 0, stream>>>(
        qTb, kTb, vTb, attn_bias, mask, attnb, avg_out);

    out_proj<<<dim3(64, 4), dim3(256), 0, stream>>>(attnb, Wob, out_b, out);
}